// Round 1
// baseline (41340.997 us; speedup 1.0000x reference)
//
#include <hip/hip_runtime.h>
#include <cmath>

#define LN 256
#define MM 8
#define HIDN 1024
#define NSTEP 2047
#define NWG 32
#define TPB 256
#define W1R 32      // W1 rows per WG (HID/NWG)
#define GR 8        // state rows per WG (L/NWG)
#define ZUN (LN+MM) // 264

#define KAPPA 0.65f
#define GAMMA 0.41f
#define TAUC 0.98f
#define INV_HALPHA 3.125f
#define RHOC 0.34f
#define V0C 0.04f
#define ALPHA 0.1f
#define LOG2_1MRHO (-0.5994620717f)

// ---- LDS layout (floats) ----
#define OFF_W1 0
#define N_W1 (W1R*ZUN)          // 8448
#define OFF_W2 (OFF_W1+N_W1)
#define N_W2 (W1R*LN)           // 8192 (transposed slice: [c][r])
#define OFF_A (OFF_W2+N_W2)
#define N_A (GR*LN)             // 2048
#define OFF_B (OFF_A+N_A)
#define N_B (MM*GR*LN)          // 16384
#define OFF_C (OFF_B+N_B)
#define N_C (GR*MM)             // 64
#define OFF_B1 (OFF_C+N_C)
#define N_B1 (W1R)
#define OFF_B2 (OFF_B1+N_B1)
#define N_B2 (GR)
#define OFF_ZU (OFF_B2+N_B2)
#define N_ZU (ZUN)
#define OFF_H (OFF_ZU+N_ZU)
#define N_H (W1R)
#define OFF_P (OFF_H+N_H)
#define N_P (GR)
#define SMEM_FLOATS (OFF_P+N_P) // 35480
#define SMEM_BYTES (SMEM_FLOATS*4)

// d_ws layout: [0] barrier counter (uint), partials at byte offset 1024:
//   part[2][NWG][LN] floats  (ping-pong)
#define WS_PART_OFF 1024

__global__ void dcm_init(unsigned int* cnt) { *cnt = 0u; }

__global__ void __launch_bounds__(TPB, 1) dcm_kernel(
    const float* __restrict__ Ag, const float* __restrict__ Bg,
    const float* __restrict__ Cg, const float* __restrict__ W1g,
    const float* __restrict__ b1g, const float* __restrict__ W2g,
    const float* __restrict__ b2g, const float* __restrict__ Ug,
    const float* __restrict__ Tg, float* __restrict__ outg,
    float* __restrict__ part, unsigned int* __restrict__ cnt)
{
  extern __shared__ float sm[];
  const int wg = blockIdx.x, tid = threadIdx.x;
  float* w1s = sm + OFF_W1;
  float* w2s = sm + OFF_W2;
  float* as_ = sm + OFF_A;
  float* bs_ = sm + OFF_B;
  float* cs_ = sm + OFF_C;
  float* b1s = sm + OFF_B1;
  float* b2s = sm + OFF_B2;
  float* zu  = sm + OFF_ZU;
  float* hsh = sm + OFF_H;
  float* pts = sm + OFF_P;

  // ---- stage weights into LDS (once) ----
  for (int i = tid; i < N_W1; i += TPB) {
    int r = i / ZUN, k = i - r * ZUN;
    w1s[i] = W1g[(wg * W1R + r) * ZUN + k];
  }
  for (int i = tid; i < N_W2; i += TPB) {
    int c = i >> 8, r = i & (LN - 1);
    w2s[i] = W2g[r * HIDN + wg * W1R + c];   // transposed: w2s[c][r]
  }
  for (int i = tid; i < N_A; i += TPB) {
    int r = i >> 8, k = i & (LN - 1);
    as_[i] = Ag[(wg * GR + r) * LN + k];
  }
  for (int i = tid; i < N_B; i += TPB) {
    int m = i / (GR * LN); int rem = i - m * GR * LN;
    int r = rem >> 8, k = rem & (LN - 1);
    bs_[i] = Bg[(m * LN + wg * GR + r) * LN + k];
  }
  for (int i = tid; i < N_C; i += TPB) {
    int r = i >> 3, m = i & 7;
    cs_[i] = Cg[(wg * GR + r) * MM + m];
  }
  for (int i = tid; i < N_B1; i += TPB) b1s[i] = b1g[wg * W1R + i];
  for (int i = tid; i < N_B2; i += TPB) b2s[i] = b2g[wg * GR + i];

  // ---- init state (replicated; thread tid owns element l = tid) ----
  float zb = 0.f, sb = 0.f, fb = 1.f, vb = 1.f, qb = 1.f;
  zu[tid] = 0.f;

  if (wg == 0) {  // output row 0
    outg[tid] = 0.f;
    outg[LN + tid] = 0.f;
    outg[2 * LN + tid] = 1.f;
    outg[3 * LN + tid] = 1.f;
    outg[4 * LN + tid] = 1.f;
    outg[(size_t)2048 * 1280 + tid] = 0.f;
  }

  int pp = 0;
  unsigned nbar = 0;

  for (int t = 0; t < NSTEP; ++t) {
    float hstep = Tg[t + 1] - Tg[t];
    float zst = zb, sst = sb, fst = fb, vst = vb, qst = qb;
    float kz = 0.f, ks = 0.f, kf = 0.f, kv = 0.f, kq = 0.f;

    for (int st = 0; st < 4; ++st) {
      int usel = (st == 0) ? (2 * t) : (st == 3) ? (2 * t + 2) : (2 * t + 1);
      if (tid < MM) zu[LN + tid] = Ug[usel * MM + tid];
      __syncthreads();                      // zu (z + u) visible

      float uu[MM];
      #pragma unroll
      for (int m = 0; m < MM; ++m) uu[m] = zu[LN + m];

      // ---- h = tanh(W1 @ zu + b1), own 32 rows; 8 lanes per row ----
      {
        int row = tid >> 3, sub = tid & 7;
        const float* wrow = w1s + row * ZUN + sub * 33;
        const float* zrow = zu + sub * 33;
        float acc = 0.f;
        #pragma unroll
        for (int j = 0; j < 33; ++j) acc += wrow[j] * zrow[j];
        acc += __shfl_xor(acc, 1);
        acc += __shfl_xor(acc, 2);
        acc += __shfl_xor(acc, 4);
        if (sub == 0) hsh[row] = tanhf(acc + b1s[row]);
      }
      // ---- p = (A + sum_m u_m B_m) @ z + C@u + alpha*b2, own 8 rows ----
      {
        int grow = tid >> 5, gsub = tid & 31;
        const float* arow = as_ + grow * LN;
        float ga = 0.f;
        #pragma unroll
        for (int j = 0; j < 8; ++j) {
          int k = gsub + 32 * j;
          float w = arow[k];
          #pragma unroll
          for (int m = 0; m < MM; ++m) w += uu[m] * bs_[(m * GR + grow) * LN + k];
          ga += w * zu[k];
        }
        ga += __shfl_xor(ga, 1);
        ga += __shfl_xor(ga, 2);
        ga += __shfl_xor(ga, 4);
        ga += __shfl_xor(ga, 8);
        ga += __shfl_xor(ga, 16);
        if (gsub == 0) {
          float cu = 0.f;
          #pragma unroll
          for (int m = 0; m < MM; ++m) cu += cs_[grow * MM + m] * uu[m];
          pts[grow] = ga + cu + ALPHA * b2s[grow];
        }
      }
      __syncthreads();                      // hsh, pts visible

      // ---- column-partial of alpha*W2@h + own exact rows; write to global ----
      {
        float a2 = 0.f;
        #pragma unroll 8
        for (int c = 0; c < W1R; ++c) a2 += w2s[c * LN + tid] * hsh[c];
        float pr = ALPHA * a2;
        int rl = tid - wg * GR;
        if (rl >= 0 && rl < GR) pr += pts[rl];
        part[((pp * NWG) + wg) * LN + tid] = pr;
      }
      __syncthreads();                      // all partial stores issued+drained

      // ---- single device-wide barrier per dyn ----
      if (tid == 0) {
        __threadfence();
        __hip_atomic_fetch_add(cnt, 1u, __ATOMIC_ACQ_REL, __HIP_MEMORY_SCOPE_AGENT);
        ++nbar;
        unsigned target = nbar * NWG;
        while (__hip_atomic_load(cnt, __ATOMIC_RELAXED, __HIP_MEMORY_SCOPE_AGENT) < target)
          __builtin_amdgcn_s_sleep(1);
        __threadfence();
      }
      __syncthreads();

      // ---- reduce partials -> dz[l=tid] (replicated, deterministic order) ----
      float dz = 0.f;
      #pragma unroll
      for (int g = 0; g < NWG; ++g) dz += part[(pp * NWG + g) * LN + tid];

      // ---- hemodynamic elementwise (replicated) ----
      float ds = zst - KAPPA * sst - GAMMA * (fst - 1.f);
      float df = sst;
      float fv = exp2f(INV_HALPHA * log2f(vst));
      float dv = (fst - fv) / TAUC;
      float E  = 1.f - exp2f(LOG2_1MRHO / fst);
      float dq = (fst * E / RHOC - fv * qst / vst) / TAUC;

      float wk = (st == 0 || st == 3) ? 1.f : 2.f;
      kz += wk * dz; ks += wk * ds; kf += wk * df; kv += wk * dv; kq += wk * dq;

      if (st < 3) {
        float c = (st == 2) ? hstep : 0.5f * hstep;
        zst = zb + c * dz; sst = sb + c * ds; fst = fb + c * df;
        vst = vb + c * dv; qst = qb + c * dq;
        zu[tid] = zst;                      // next-stage z (no reader until next sync)
      }
      pp ^= 1;
    }

    float h6 = hstep * (1.f / 6.f);
    zb += h6 * kz; sb += h6 * ks; fb += h6 * kf; vb += h6 * kv; qb += h6 * kq;
    zu[tid] = zb;                           // z for next step's k1

    if ((t & (NWG - 1)) == wg) {            // distribute output writes
      size_t ro = (size_t)(t + 1) * 1280;
      outg[ro + tid] = zb;
      outg[ro + LN + tid] = sb;
      outg[ro + 2 * LN + tid] = fb;
      outg[ro + 3 * LN + tid] = vb;
      outg[ro + 4 * LN + tid] = qb;
      float yv = V0C * (2.38f * (1.f - qb) + 2.f * (1.f - qb / vb) + 0.48f * (1.f - vb));
      outg[(size_t)2048 * 1280 + (size_t)(t + 1) * LN + tid] = yv;
    }
  }
}

extern "C" void kernel_launch(void* const* d_in, const int* in_sizes, int n_in,
                              void* d_out, int out_size, void* d_ws, size_t ws_size,
                              hipStream_t stream) {
  const float* Ag  = (const float*)d_in[0];
  const float* Bg  = (const float*)d_in[1];
  const float* Cg  = (const float*)d_in[2];
  const float* W1g = (const float*)d_in[3];
  const float* b1g = (const float*)d_in[4];
  const float* W2g = (const float*)d_in[5];
  const float* b2g = (const float*)d_in[6];
  const float* Ug  = (const float*)d_in[7];
  const float* Tg  = (const float*)d_in[8];
  float* outg = (float*)d_out;

  unsigned int* cnt = (unsigned int*)d_ws;
  float* part = (float*)((char*)d_ws + WS_PART_OFF);

  hipFuncSetAttribute((const void*)dcm_kernel,
                      hipFuncAttributeMaxDynamicSharedMemorySize, SMEM_BYTES);

  hipLaunchKernelGGL(dcm_init, dim3(1), dim3(1), 0, stream, cnt);
  hipLaunchKernelGGL(dcm_kernel, dim3(NWG), dim3(TPB), SMEM_BYTES, stream,
                     Ag, Bg, Cg, W1g, b1g, W2g, b2g, Ug, Tg, outg, part, cnt);
}

// Round 2
// 27699.057 us; speedup vs baseline: 1.4925x; 1.4925x over previous
//
#include <hip/hip_runtime.h>
#include <cmath>

#define LN 256
#define MM 8
#define HIDN 1024
#define NSTEP 2047
#define NWG 32
#define TPB 256
#define W1R 32      // W1 rows per WG (HID/NWG)
#define GR 8        // state rows per WG (L/NWG)
#define ZUN (LN+MM) // 264

#define KAPPA 0.65f
#define GAMMA 0.41f
#define TAUC 0.98f
#define INV_HALPHA 3.125f
#define RHOC 0.34f
#define V0C 0.04f
#define ALPHA 0.1f
#define LOG2_1MRHO (-0.5994620717f)

// ---- LDS layout (floats) ----
#define OFF_W1 0
#define N_W1 (W1R*ZUN)          // 8448
#define OFF_W2 (OFF_W1+N_W1)
#define N_W2 (W1R*LN)           // 8192 (transposed slice: [c][r])
#define OFF_A (OFF_W2+N_W2)
#define N_A (GR*LN)             // 2048
#define OFF_B (OFF_A+N_A)
#define N_B (MM*GR*LN)          // 16384
#define OFF_C (OFF_B+N_B)
#define N_C (GR*MM)             // 64
#define OFF_B1 (OFF_C+N_C)
#define N_B1 (W1R)
#define OFF_B2 (OFF_B1+N_B1)
#define N_B2 (GR)
#define OFF_ZU (OFF_B2+N_B2)
#define N_ZU (ZUN)
#define OFF_H (OFF_ZU+N_ZU)
#define N_H (W1R)
#define OFF_P (OFF_H+N_H)
#define N_P (GR)
#define SMEM_FLOATS (OFF_P+N_P) // 35480
#define SMEM_BYTES (SMEM_FLOATS*4)

// d_ws layout:
//   bytes [0 .. 2048)   : flags[NWG], each on its own 64B line (stride 16 uints)
//   bytes [4096 .. )    : part[2][NWG][LN] floats (ping-pong)
#define WS_PART_OFF 4096
#define FLG_STRIDE 16

__global__ void dcm_init(unsigned int* flg) {
  flg[threadIdx.x] = 0u;   // 512 uints covers NWG*FLG_STRIDE
}

__global__ void __launch_bounds__(TPB, 1) dcm_kernel(
    const float* __restrict__ Ag, const float* __restrict__ Bg,
    const float* __restrict__ Cg, const float* __restrict__ W1g,
    const float* __restrict__ b1g, const float* __restrict__ W2g,
    const float* __restrict__ b2g, const float* __restrict__ Ug,
    const float* __restrict__ Tg, float* __restrict__ outg,
    float* __restrict__ part, unsigned int* __restrict__ flg)
{
  extern __shared__ float sm[];
  const int wg = blockIdx.x, tid = threadIdx.x;
  float* w1s = sm + OFF_W1;
  float* w2s = sm + OFF_W2;
  float* as_ = sm + OFF_A;
  float* bs_ = sm + OFF_B;
  float* cs_ = sm + OFF_C;
  float* b1s = sm + OFF_B1;
  float* b2s = sm + OFF_B2;
  float* zu  = sm + OFF_ZU;
  float* hsh = sm + OFF_H;
  float* pts = sm + OFF_P;

  // ---- stage weights into LDS (once) ----
  for (int i = tid; i < N_W1; i += TPB) {
    int r = i / ZUN, k = i - r * ZUN;
    w1s[i] = W1g[(wg * W1R + r) * ZUN + k];
  }
  for (int i = tid; i < N_W2; i += TPB) {
    int c = i >> 8, r = i & (LN - 1);
    w2s[i] = W2g[r * HIDN + wg * W1R + c];   // transposed: w2s[c][r]
  }
  for (int i = tid; i < N_A; i += TPB) {
    int r = i >> 8, k = i & (LN - 1);
    as_[i] = Ag[(wg * GR + r) * LN + k];
  }
  for (int i = tid; i < N_B; i += TPB) {
    int m = i / (GR * LN); int rem = i - m * GR * LN;
    int r = rem >> 8, k = rem & (LN - 1);
    bs_[i] = Bg[(m * LN + wg * GR + r) * LN + k];
  }
  for (int i = tid; i < N_C; i += TPB) {
    int r = i >> 3, m = i & 7;
    cs_[i] = Cg[(wg * GR + r) * MM + m];
  }
  for (int i = tid; i < N_B1; i += TPB) b1s[i] = b1g[wg * W1R + i];
  for (int i = tid; i < N_B2; i += TPB) b2s[i] = b2g[wg * GR + i];

  // ---- init state (replicated; thread tid owns element l = tid) ----
  float zb = 0.f, sb = 0.f, fb = 1.f, vb = 1.f, qb = 1.f;
  zu[tid] = 0.f;

  if (wg == 0) {  // output row 0
    outg[tid] = 0.f;
    outg[LN + tid] = 0.f;
    outg[2 * LN + tid] = 1.f;
    outg[3 * LN + tid] = 1.f;
    outg[4 * LN + tid] = 1.f;
    outg[(size_t)2048 * 1280 + tid] = 0.f;
  }

  int pp = 0;

  for (int t = 0; t < NSTEP; ++t) {
    float hstep = Tg[t + 1] - Tg[t];
    float zst = zb, sst = sb, fst = fb, vst = vb, qst = qb;
    float kz = 0.f, ks = 0.f, kf = 0.f, kv = 0.f, kq = 0.f;

    for (int st = 0; st < 4; ++st) {
      int usel = (st == 0) ? (2 * t) : (st == 3) ? (2 * t + 2) : (2 * t + 1);
      if (tid < MM) zu[LN + tid] = Ug[usel * MM + tid];
      __syncthreads();                      // zu (z + u) visible

      float uu[MM];
      #pragma unroll
      for (int m = 0; m < MM; ++m) uu[m] = zu[LN + m];

      // ---- h = tanh(W1 @ zu + b1), own 32 rows; 8 lanes per row ----
      {
        int row = tid >> 3, sub = tid & 7;
        const float* wrow = w1s + row * ZUN + sub * 33;
        const float* zrow = zu + sub * 33;
        float acc = 0.f;
        #pragma unroll
        for (int j = 0; j < 33; ++j) acc += wrow[j] * zrow[j];
        acc += __shfl_xor(acc, 1);
        acc += __shfl_xor(acc, 2);
        acc += __shfl_xor(acc, 4);
        if (sub == 0) hsh[row] = tanhf(acc + b1s[row]);
      }
      // ---- p = (A + sum_m u_m B_m) @ z + C@u + alpha*b2, own 8 rows ----
      {
        int grow = tid >> 5, gsub = tid & 31;
        const float* arow = as_ + grow * LN;
        float ga = 0.f;
        #pragma unroll
        for (int j = 0; j < 8; ++j) {
          int k = gsub + 32 * j;
          float w = arow[k];
          #pragma unroll
          for (int m = 0; m < MM; ++m) w += uu[m] * bs_[(m * GR + grow) * LN + k];
          ga += w * zu[k];
        }
        ga += __shfl_xor(ga, 1);
        ga += __shfl_xor(ga, 2);
        ga += __shfl_xor(ga, 4);
        ga += __shfl_xor(ga, 8);
        ga += __shfl_xor(ga, 16);
        if (gsub == 0) {
          float cu = 0.f;
          #pragma unroll
          for (int m = 0; m < MM; ++m) cu += cs_[grow * MM + m] * uu[m];
          pts[grow] = ga + cu + ALPHA * b2s[grow];
        }
      }
      __syncthreads();                      // hsh, pts visible

      // ---- column-partial of alpha*W2@h + own exact rows ----
      float pr;
      {
        float a2 = 0.f;
        #pragma unroll 8
        for (int c = 0; c < W1R; ++c) a2 += w2s[c * LN + tid] * hsh[c];
        pr = ALPHA * a2;
        int rl = tid - wg * GR;
        if (rl >= 0 && rl < GR) pr += pts[rl];
      }
      // write-through store to coherence point (bypasses local L2)
      __hip_atomic_store(&part[((pp * NWG) + wg) * LN + tid], pr,
                         __ATOMIC_RELAXED, __HIP_MEMORY_SCOPE_AGENT);

      // ---- hemodynamic elementwise (local; overlap with store latency) ----
      float ds = zst - KAPPA * sst - GAMMA * (fst - 1.f);
      float df = sst;
      float fv = exp2f(INV_HALPHA * log2f(vst));
      float dv = (fst - fv) / TAUC;
      float E  = 1.f - exp2f(LOG2_1MRHO / fst);
      float dq = (fst * E / RHOC - fv * qst / vst) / TAUC;

      __syncthreads();   // implies s_waitcnt vmcnt(0): partials acked at coherence point

      unsigned e = (unsigned)(4 * t + st + 1);
      if (tid == 0)
        __hip_atomic_store(&flg[wg * FLG_STRIDE], e,
                           __ATOMIC_RELAXED, __HIP_MEMORY_SCOPE_AGENT);

      // ---- poll all 32 flags (each wave independently; lane l polls flag l&31)
      {
        const unsigned* fp_ = &flg[(tid & 31) * FLG_STRIDE];
        for (;;) {
          unsigned v = __hip_atomic_load(fp_, __ATOMIC_RELAXED,
                                         __HIP_MEMORY_SCOPE_AGENT);
          if (__ballot(v >= e) == 0xFFFFFFFFFFFFFFFFull) break;
        }
      }

      // ---- reduce partials -> dz[l=tid] (cache-bypass loads, fixed order) ----
      float dz = 0.f;
      #pragma unroll
      for (int g = 0; g < NWG; ++g)
        dz += __hip_atomic_load(&part[(pp * NWG + g) * LN + tid],
                                __ATOMIC_RELAXED, __HIP_MEMORY_SCOPE_AGENT);

      float wk = (st == 0 || st == 3) ? 1.f : 2.f;
      kz += wk * dz; ks += wk * ds; kf += wk * df; kv += wk * dv; kq += wk * dq;

      if (st < 3) {
        float c = (st == 2) ? hstep : 0.5f * hstep;
        zst = zb + c * dz; sst = sb + c * ds; fst = fb + c * df;
        vst = vb + c * dv; qst = qb + c * dq;
        zu[tid] = zst;                      // next-stage z (no reader until next sync)
      }
      pp ^= 1;
    }

    float h6 = hstep * (1.f / 6.f);
    zb += h6 * kz; sb += h6 * ks; fb += h6 * kf; vb += h6 * kv; qb += h6 * kq;
    zu[tid] = zb;                           // z for next step's k1

    if ((t & (NWG - 1)) == wg) {            // distribute output writes
      size_t ro = (size_t)(t + 1) * 1280;
      outg[ro + tid] = zb;
      outg[ro + LN + tid] = sb;
      outg[ro + 2 * LN + tid] = fb;
      outg[ro + 3 * LN + tid] = vb;
      outg[ro + 4 * LN + tid] = qb;
      float yv = V0C * (2.38f * (1.f - qb) + 2.f * (1.f - qb / vb) + 0.48f * (1.f - vb));
      outg[(size_t)2048 * 1280 + (size_t)(t + 1) * LN + tid] = yv;
    }
  }
}

extern "C" void kernel_launch(void* const* d_in, const int* in_sizes, int n_in,
                              void* d_out, int out_size, void* d_ws, size_t ws_size,
                              hipStream_t stream) {
  const float* Ag  = (const float*)d_in[0];
  const float* Bg  = (const float*)d_in[1];
  const float* Cg  = (const float*)d_in[2];
  const float* W1g = (const float*)d_in[3];
  const float* b1g = (const float*)d_in[4];
  const float* W2g = (const float*)d_in[5];
  const float* b2g = (const float*)d_in[6];
  const float* Ug  = (const float*)d_in[7];
  const float* Tg  = (const float*)d_in[8];
  float* outg = (float*)d_out;

  unsigned int* flg = (unsigned int*)d_ws;
  float* part = (float*)((char*)d_ws + WS_PART_OFF);

  hipFuncSetAttribute((const void*)dcm_kernel,
                      hipFuncAttributeMaxDynamicSharedMemorySize, SMEM_BYTES);

  hipLaunchKernelGGL(dcm_init, dim3(1), dim3(512), 0, stream, flg);
  hipLaunchKernelGGL(dcm_kernel, dim3(NWG), dim3(TPB), SMEM_BYTES, stream,
                     Ag, Bg, Cg, W1g, b1g, W2g, b2g, Ug, Tg, outg, part, flg);
}